// Round 3
// baseline (630.411 us; speedup 1.0000x reference)
//
#include <hip/hip_runtime.h>
#include <math.h>

#define EPSD 1e-5

// ---------------- f64 reduction helpers (256-thread blocks = 4 waves) ----------------

__device__ __forceinline__ double waveReduceSumD(double v) {
#pragma unroll
    for (int off = 32; off > 0; off >>= 1)
        v += __shfl_down(v, off, 64);
    return v;
}

// Returns total to ALL threads. buf must be shared double[4]. Requires 256 threads.
__device__ __forceinline__ double blockReduceSumD(double v, double* buf) {
    int lane = threadIdx.x & 63;
    int w = threadIdx.x >> 6;
    v = waveReduceSumD(v);
    __syncthreads();
    if (lane == 0) buf[w] = v;
    __syncthreads();
    return buf[0] + buf[1] + buf[2] + buf[3];
}

// Build 26-entry entropy table: tab[cnt] = -(cnt/25)*log(clip(cnt/25,1e-5,1-1e-5))
__device__ __forceinline__ void build_ent_tab(double* tab) {
    int t = threadIdx.x;
    if (t < 26) {
        if (t == 0) tab[0] = 0.0;   // pk=0 -> -0*log(1e-5) == 0
        else {
            double pk = (double)t / 25.0;
            double cl = fmin(fmax(pk, 1e-5), 1.0 - 1e-5);
            tab[t] = -pk * log(cl);
        }
    }
}

// ---------------- entropy over 5x5 patches of an 18x18 channel in LDS (f64) ----------------
// Thread t < 196 handles patch (t/14, t%14).
__device__ __forceinline__ double patch_entropy_d(const double* vals, const double* tab) {
    int t = threadIdx.x;
    if (t >= 196) return 0.0;
    int py = t / 14, px = t - py * 14;
    double pv[25];
#pragma unroll
    for (int i = 0; i < 5; i++)
#pragma unroll
        for (int j = 0; j < 5; j++)
            pv[i * 5 + j] = vals[(py + i) * 18 + px + j];
    double mn = pv[0], mx = pv[0];
#pragma unroll
    for (int k = 1; k < 25; k++) { mn = fmin(mn, pv[k]); mx = fmax(mx, pv[k]); }
    double rng = (mx > mn) ? (mx - mn) : 1.0;
    // histogram packed as 5-bit fields: a0 = bins 0..11, a1 = bins 12..23, a2 = bin 24
    unsigned long long a0 = 0ull, a1 = 0ull;
    int a2 = 0;
#pragma unroll
    for (int k = 0; k < 25; k++) {
        double tt = (pv[k] - mn) / rng * 25.0;   // match reference op order
        int bi = (int)floor(tt);
        bi = bi < 0 ? 0 : (bi > 24 ? 24 : bi);
        unsigned sh0 = ((unsigned)(5 * bi)) & 63u;
        unsigned sh1 = ((unsigned)(5 * bi - 60)) & 63u;
        a0 += (bi < 12) ? (1ull << sh0) : 0ull;
        a1 += (bi >= 12 && bi < 24) ? (1ull << sh1) : 0ull;
        a2 += (bi == 24) ? 1 : 0;
    }
    double ent = 0.0;
#pragma unroll
    for (int k = 0; k < 12; k++) ent += tab[(a0 >> (5 * k)) & 31ull];
#pragma unroll
    for (int k = 0; k < 12; k++) ent += tab[(a1 >> (5 * k)) & 31ull];
    ent += tab[a2];
    return ent;
}

// Shared epilogue for the two entropy-IN stages (f64). s/s2 are this thread's
// partials over ALL pixels it computed (strided over 324).
__device__ __forceinline__ void in_ent_epilogue_d(const double* vals, double* rbuf,
                                                  const double* tab,
                                                  double s, double s2,
                                                  double gamma, double beta,
                                                  double* __restrict__ outp) {
    double ent = patch_entropy_d(vals, tab);
    double entmean = blockReduceSumD(ent, rbuf) / 196.0;
    double ssum  = blockReduceSumD(s, rbuf);
    double s2sum = blockReduceSumD(s2, rbuf);
    double mean = ssum / 324.0;
    double varb = s2sum / 324.0 - mean * mean;          // biased
    double varu = varb * (324.0 / 323.0);               // unbiased (torch default)
    double rstd = 1.0 / sqrt(varu + EPSD);
    double sc = gamma * entmean * rstd;
    for (int idx = threadIdx.x; idx < 324; idx += 256) {   // FIX: strided (was if t<324 with 256 threads)
        double v = (vals[idx] - mean) * sc + beta;
        outp[idx] = fmax(v, 0.0);
    }
}

// ---------------- stage A: conv0 (3->8, 7x7, s4, p2) + per-channel GN + ReLU ----------------
// One block per (b, c): 512 blocks, 256 threads.
__global__ __launch_bounds__(256) void k_conv0_gn(const float* __restrict__ x,
                                                  const float* __restrict__ w,
                                                  const float* __restrict__ bias,
                                                  const float* __restrict__ gw,
                                                  const float* __restrict__ gb,
                                                  double* __restrict__ out) {
    __shared__ double vals[3136];
    __shared__ double wsh[147];
    __shared__ double rbuf[4];
    int b = blockIdx.x >> 3;
    int c = blockIdx.x & 7;
    int t = threadIdx.x;
    for (int i = t; i < 147; i += 256) wsh[i] = (double)w[c * 147 + i];
    __syncthreads();
    const float* xb = x + (size_t)b * 3 * 224 * 224;
    double bv = (double)bias[c];
    double s = 0.0, s2 = 0.0;
    for (int idx = t; idx < 3136; idx += 256) {
        int oy = idx / 56, ox = idx - oy * 56;
        int y0 = oy * 4 - 2, x0 = ox * 4 - 2;
        double acc = bv;
        for (int ci = 0; ci < 3; ci++) {
            const float* xp = xb + ci * 224 * 224;
            const double* wp = wsh + ci * 49;
#pragma unroll
            for (int ky = 0; ky < 7; ky++) {
                int iy = y0 + ky;
                if (iy < 0 || iy >= 224) continue;
#pragma unroll
                for (int kx = 0; kx < 7; kx++) {
                    int ix = x0 + kx;
                    if (ix < 0 || ix >= 224) continue;
                    acc += (double)xp[iy * 224 + ix] * wp[ky * 7 + kx];
                }
            }
        }
        vals[idx] = acc;
        s += acc; s2 += acc * acc;
    }
    double ssum  = blockReduceSumD(s, rbuf);
    double s2sum = blockReduceSumD(s2, rbuf);
    double mean = ssum / 3136.0;
    double var  = s2sum / 3136.0 - mean * mean;         // biased (GN)
    double rstd = 1.0 / sqrt(var + EPSD);
    double sc = (double)gw[c] * rstd;
    double sh = (double)gb[c] - mean * sc;
    double* outp = out + ((size_t)b * 8 + c) * 3136;
    for (int idx = t; idx < 3136; idx += 256) {
        double v = vals[idx] * sc + sh;
        outp[idx] = fmax(v, 0.0);
    }
}

// ---------------- stage B: conv1 (8->16, 5x5, s3, p1) + entropy-IN + ReLU ----------------
// One block per (b, c): 1024 blocks, 256 threads.
__global__ __launch_bounds__(256) void k_conv1_ent(const double* __restrict__ in,
                                                   const float* __restrict__ w,
                                                   const float* __restrict__ bias,
                                                   const float* __restrict__ nw,
                                                   const float* __restrict__ nb,
                                                   double* __restrict__ out) {
    __shared__ double vals[324];
    __shared__ double wsh[200];
    __shared__ double rbuf[4];
    __shared__ double tab[26];
    int b = blockIdx.x >> 4;
    int c = blockIdx.x & 15;
    int t = threadIdx.x;
    for (int i = t; i < 200; i += 256) wsh[i] = (double)w[c * 200 + i];
    build_ent_tab(tab);
    __syncthreads();
    const double* xb = in + (size_t)b * 8 * 3136;
    double s = 0.0, s2 = 0.0;
    for (int idx = t; idx < 324; idx += 256) {   // FIX: strided loop covers all 324 pixels
        int oy = idx / 18, ox = idx - oy * 18;
        int y0 = oy * 3 - 1, x0 = ox * 3 - 1;
        double acc = (double)bias[c];
        for (int ci = 0; ci < 8; ci++) {
            const double* xp = xb + ci * 3136;
            const double* wp = wsh + ci * 25;
#pragma unroll
            for (int ky = 0; ky < 5; ky++) {
                int iy = y0 + ky;
                if (iy < 0 || iy >= 56) continue;
#pragma unroll
                for (int kx = 0; kx < 5; kx++) {
                    int ix = x0 + kx;
                    if (ix < 0 || ix >= 56) continue;
                    acc += xp[iy * 56 + ix] * wp[ky * 5 + kx];
                }
            }
        }
        vals[idx] = acc;
        s += acc; s2 += acc * acc;
    }
    __syncthreads();
    in_ent_epilogue_d(vals, rbuf, tab, s, s2, (double)nw[c], (double)nb[c],
                      out + ((size_t)b * 16 + c) * 324);
}

// ---------------- stage C: conv2 (16->32, 3x3, s1, p1) + entropy-IN + ReLU ----------------
// One block per (b, c): 2048 blocks, 256 threads. Input slab staged in LDS.
__global__ __launch_bounds__(256) void k_conv2_ent(const double* __restrict__ in,
                                                   const float* __restrict__ w,
                                                   const float* __restrict__ bias,
                                                   const float* __restrict__ nw,
                                                   const float* __restrict__ nb,
                                                   double* __restrict__ out) {
    __shared__ double xin[5184];   // 16 * 324
    __shared__ double vals[324];
    __shared__ double wsh[144];
    __shared__ double rbuf[4];
    __shared__ double tab[26];
    int b = blockIdx.x >> 5;
    int c = blockIdx.x & 31;
    int t = threadIdx.x;
    const double* xb = in + (size_t)b * 5184;
    for (int i = t; i < 5184; i += 256) xin[i] = xb[i];
    for (int i = t; i < 144; i += 256) wsh[i] = (double)w[c * 144 + i];
    build_ent_tab(tab);
    __syncthreads();
    double s = 0.0, s2 = 0.0;
    for (int idx = t; idx < 324; idx += 256) {   // FIX: strided loop covers all 324 pixels
        int oy = idx / 18, ox = idx - oy * 18;
        double acc = (double)bias[c];
        for (int ci = 0; ci < 16; ci++) {
            const double* xp = xin + ci * 324;
            const double* wp = wsh + ci * 9;
#pragma unroll
            for (int ky = 0; ky < 3; ky++) {
                int iy = oy + ky - 1;
                if (iy < 0 || iy >= 18) continue;
#pragma unroll
                for (int kx = 0; kx < 3; kx++) {
                    int ix = ox + kx - 1;
                    if (ix < 0 || ix >= 18) continue;
                    acc += xp[iy * 18 + ix] * wp[ky * 3 + kx];
                }
            }
        }
        vals[idx] = acc;
        s += acc; s2 += acc * acc;
    }
    __syncthreads();
    in_ent_epilogue_d(vals, rbuf, tab, s, s2, (double)nw[c], (double)nb[c],
                      out + ((size_t)b * 32 + c) * 324);
}

// ---------------- stage D1: BatchNorm1d batch stats folded to scale/shift (f64) ----------------
__global__ __launch_bounds__(256) void k_bnstats(const double* __restrict__ h2,
                                                 const float* __restrict__ g,
                                                 const float* __restrict__ bb,
                                                 double* __restrict__ scale,
                                                 double* __restrict__ shift) {
    int f = blockIdx.x * 256 + threadIdx.x;
    if (f >= 10368) return;
    double s = 0.0, s2 = 0.0;
    for (int b = 0; b < 64; b++) {
        double v = h2[(size_t)b * 10368 + f];
        s += v; s2 += v * v;
    }
    double mean = s / 64.0;
    double var = s2 / 64.0 - mean * mean;   // biased (BN training)
    double rstd = 1.0 / sqrt(var + EPSD);
    double sc = (double)g[f] * rstd;
    scale[f] = sc;
    shift[f] = (double)bb[f] - mean * sc;
}

// ---------------- stage D2: fc1 with folded BN, + ReLU (f64) ----------------
// One block per (b, j): 2048 blocks.
__global__ __launch_bounds__(256) void k_fc1(const double* __restrict__ h2,
                                             const double* __restrict__ scale,
                                             const double* __restrict__ shift,
                                             const float* __restrict__ w1,
                                             const float* __restrict__ b1,
                                             double* __restrict__ fcout) {
    __shared__ double rbuf[4];
    int b = blockIdx.x >> 5;
    int j = blockIdx.x & 31;
    const double* hb = h2 + (size_t)b * 10368;
    const float* wj = w1 + (size_t)j * 10368;
    double acc = 0.0;
    for (int f = threadIdx.x; f < 10368; f += 256)
        acc += (hb[f] * scale[f] + shift[f]) * (double)wj[f];
    acc = blockReduceSumD(acc, rbuf);
    if (threadIdx.x == 0)
        fcout[b * 32 + j] = fmax(acc + (double)b1[j], 0.0);
}

// ---------------- stage E: heads + softmax (f64, outputs f32) ----------------
__global__ __launch_bounds__(64) void k_heads(const double* __restrict__ fc,
                                              const float* __restrict__ sw,
                                              const float* __restrict__ sb,
                                              const float* __restrict__ vw,
                                              const float* __restrict__ vb,
                                              float* __restrict__ out) {
    int b = threadIdx.x;
    double h[32];
#pragma unroll
    for (int i = 0; i < 32; i++) h[i] = fc[b * 32 + i];
    // shape head: 5-way softmax
    double lg[5];
    double mx = -1e300;
#pragma unroll
    for (int k = 0; k < 5; k++) {
        double a = (double)sb[k];
#pragma unroll
        for (int i = 0; i < 32; i++) a += h[i] * (double)sw[k * 32 + i];
        lg[k] = a;
        mx = fmax(mx, a);
    }
    double se = 0.0;
#pragma unroll
    for (int k = 0; k < 5; k++) { lg[k] = exp(lg[k] - mx); se += lg[k]; }
#pragma unroll
    for (int k = 0; k < 5; k++) out[b * 5 + k] = (float)(lg[k] / se);
    // vern head: 2-way softmax
    double l0 = (double)vb[0], l1 = (double)vb[1];
#pragma unroll
    for (int i = 0; i < 32; i++) { l0 += h[i] * (double)vw[i]; l1 += h[i] * (double)vw[32 + i]; }
    double m = fmax(l0, l1);
    double e0 = exp(l0 - m), e1 = exp(l1 - m);
    double inv = 1.0 / (e0 + e1);
    out[320 + b * 2 + 0] = (float)(e0 * inv);
    out[320 + b * 2 + 1] = (float)(e1 * inv);
}

// ---------------- host launcher ----------------
extern "C" void kernel_launch(void* const* d_in, const int* in_sizes, int n_in,
                              void* d_out, int out_size, void* d_ws, size_t ws_size,
                              hipStream_t stream) {
    const float* x       = (const float*)d_in[0];
    const float* conv0_w = (const float*)d_in[1];
    const float* conv0_b = (const float*)d_in[2];
    const float* conv1_w = (const float*)d_in[3];
    const float* conv1_b = (const float*)d_in[4];
    const float* conv2_w = (const float*)d_in[5];
    const float* conv2_b = (const float*)d_in[6];
    const float* gn0_w   = (const float*)d_in[7];
    const float* gn0_b   = (const float*)d_in[8];
    const float* n1_w    = (const float*)d_in[9];
    const float* n1_b    = (const float*)d_in[10];
    const float* n2_w    = (const float*)d_in[11];
    const float* n2_b    = (const float*)d_in[12];
    const float* bn_g    = (const float*)d_in[13];
    const float* bn_b    = (const float*)d_in[14];
    const float* fc1_w   = (const float*)d_in[15];
    const float* fc1_b   = (const float*)d_in[16];
    const float* shape_w = (const float*)d_in[17];
    const float* shape_b = (const float*)d_in[18];
    const float* vern_w  = (const float*)d_in[19];
    const float* vern_b  = (const float*)d_in[20];
    float* out = (float*)d_out;

    double* ws = (double*)d_ws;
    double* h0    = ws;                    // 64*8*56*56   = 1605632
    double* h1    = h0 + 1605632;          // 64*16*18*18  = 331776
    double* h2    = h1 + 331776;           // 64*32*18*18  = 663552
    double* scale = h2 + 663552;           // 10368
    double* shift = scale + 10368;         // 10368
    double* fc    = shift + 10368;         // 64*32

    k_conv0_gn<<<dim3(512), dim3(256), 0, stream>>>(x, conv0_w, conv0_b, gn0_w, gn0_b, h0);
    k_conv1_ent<<<dim3(1024), dim3(256), 0, stream>>>(h0, conv1_w, conv1_b, n1_w, n1_b, h1);
    k_conv2_ent<<<dim3(2048), dim3(256), 0, stream>>>(h1, conv2_w, conv2_b, n2_w, n2_b, h2);
    k_bnstats<<<dim3(41), dim3(256), 0, stream>>>(h2, bn_g, bn_b, scale, shift);
    k_fc1<<<dim3(2048), dim3(256), 0, stream>>>(h2, scale, shift, fc1_w, fc1_b, fc);
    k_heads<<<dim3(1), dim3(64), 0, stream>>>(fc, shape_w, shape_b, vern_w, vern_b, out);
}

// Round 4
// 418.549 us; speedup vs baseline: 1.5062x; 1.5062x over previous
//
#include <hip/hip_runtime.h>
#include <math.h>

#define EPSD 1e-5

// ---------------- f64 block reduction (NW waves) ----------------

__device__ __forceinline__ double waveReduceSumD(double v) {
#pragma unroll
    for (int off = 32; off > 0; off >>= 1)
        v += __shfl_down(v, off, 64);
    return v;
}

template <int NW>
__device__ __forceinline__ double blockReduceSumD(double v, double* buf) {
    int lane = threadIdx.x & 63;
    int w = threadIdx.x >> 6;
    v = waveReduceSumD(v);
    __syncthreads();
    if (lane == 0) buf[w] = v;
    __syncthreads();
    double tot = 0.0;
#pragma unroll
    for (int i = 0; i < NW; i++) tot += buf[i];
    return tot;
}

// Build 26-entry entropy table: tab[cnt] = -(cnt/25)*log(clip(cnt/25,1e-5,1-1e-5))
__device__ __forceinline__ void build_ent_tab(float* tab) {
    int t = threadIdx.x;
    if (t < 26) {
        if (t == 0) tab[0] = 0.f;
        else {
            double pk = (double)t / 25.0;
            double cl = fmin(fmax(pk, 1e-5), 1.0 - 1e-5);
            tab[t] = (float)(-pk * log(cl));
        }
    }
}

// ---------------- entropy over 5x5 patches of an 18x18 channel in LDS (f32) ----------------
__device__ __forceinline__ float patch_entropy_f(const float* vals, const float* tab) {
    int t = threadIdx.x;
    if (t >= 196) return 0.f;
    int py = t / 14, px = t - py * 14;
    float pv[25];
#pragma unroll
    for (int i = 0; i < 5; i++)
#pragma unroll
        for (int j = 0; j < 5; j++)
            pv[i * 5 + j] = vals[(py + i) * 18 + px + j];
    float mn = pv[0], mx = pv[0];
#pragma unroll
    for (int k = 1; k < 25; k++) { mn = fminf(mn, pv[k]); mx = fmaxf(mx, pv[k]); }
    float rng = (mx > mn) ? (mx - mn) : 1.0f;
    unsigned long long a0 = 0ull, a1 = 0ull;
    int a2 = 0;
#pragma unroll
    for (int k = 0; k < 25; k++) {
        float tt = (pv[k] - mn) / rng * 25.0f;   // keep reference op order
        int bi = (int)floorf(tt);
        bi = bi < 0 ? 0 : (bi > 24 ? 24 : bi);
        unsigned sh0 = ((unsigned)(5 * bi)) & 63u;
        unsigned sh1 = ((unsigned)(5 * bi - 60)) & 63u;
        a0 += (bi < 12) ? (1ull << sh0) : 0ull;
        a1 += (bi >= 12 && bi < 24) ? (1ull << sh1) : 0ull;
        a2 += (bi == 24) ? 1 : 0;
    }
    float ent = 0.f;
#pragma unroll
    for (int k = 0; k < 12; k++) ent += tab[(a0 >> (5 * k)) & 31ull];
#pragma unroll
    for (int k = 0; k < 12; k++) ent += tab[(a1 >> (5 * k)) & 31ull];
    ent += tab[a2];
    return ent;
}

// Epilogue for entropy-IN stages (256 threads). vals[324] complete in LDS; s/s2 f64 partials.
__device__ __forceinline__ void in_ent_epilogue(const float* vals, double* rbuf,
                                                const float* tab,
                                                double s, double s2,
                                                double gamma, double beta,
                                                float* __restrict__ outp) {
    double ent = (double)patch_entropy_f(vals, tab);
    double entmean = blockReduceSumD<4>(ent, rbuf) / 196.0;
    double ssum  = blockReduceSumD<4>(s, rbuf);
    double s2sum = blockReduceSumD<4>(s2, rbuf);
    double mean = ssum / 324.0;
    double varb = s2sum / 324.0 - mean * mean;
    double varu = varb * (324.0 / 323.0);               // unbiased (torch default)
    double rstd = 1.0 / sqrt(varu + EPSD);
    float sc = (float)(gamma * entmean * rstd);
    float mu = (float)mean;
    float be = (float)beta;
    for (int idx = threadIdx.x; idx < 324; idx += 256) {
        float v = (vals[idx] - mu) * sc + be;
        outp[idx] = fmaxf(v, 0.f);
    }
}

// ---------------- stage A: conv0 (3->8, 7x7, s4, p2) + per-channel GN + ReLU ----------------
// One block per (b, c): 512 blocks, 1024 threads (2 blocks/CU = full thread occupancy).
__global__ __launch_bounds__(1024) void k_conv0_gn(const float* __restrict__ x,
                                                   const float* __restrict__ w,
                                                   const float* __restrict__ bias,
                                                   const float* __restrict__ gw,
                                                   const float* __restrict__ gb,
                                                   float* __restrict__ out) {
    __shared__ float vals[3136];
    __shared__ float wsh[147];
    __shared__ double rbuf[16];
    int b = blockIdx.x >> 3;
    int c = blockIdx.x & 7;
    int t = threadIdx.x;
    for (int i = t; i < 147; i += 1024) wsh[i] = w[c * 147 + i];
    __syncthreads();
    const float* xb = x + (size_t)b * 3 * 224 * 224;
    float bv = bias[c];
    double s = 0.0, s2 = 0.0;
    // interior pixels: oy,ox in [1,54] -> guard-free fully-unrolled 7x7x3
    for (int i = t; i < 2916; i += 1024) {
        int oy = 1 + i / 54, ox = 1 + i % 54;
        int y0 = oy * 4 - 2, x0 = ox * 4 - 2;
        float acc = bv;
#pragma unroll
        for (int ci = 0; ci < 3; ci++) {
            const float* xp = xb + ci * 224 * 224 + y0 * 224 + x0;
            const float* wp = wsh + ci * 49;
#pragma unroll
            for (int ky = 0; ky < 7; ky++) {
#pragma unroll
                for (int kx = 0; kx < 7; kx++)
                    acc += xp[ky * 224 + kx] * wp[ky * 7 + kx];
            }
        }
        vals[oy * 56 + ox] = acc;
        s += (double)acc; s2 += (double)acc * (double)acc;
    }
    // boundary pixels: 220 of them, clamped-bound loops
    if (t < 220) {
        int oy, ox;
        if (t < 56)       { oy = 0;        ox = t; }
        else if (t < 112) { oy = 55;       ox = t - 56; }
        else if (t < 166) { oy = t - 111;  ox = 0; }
        else              { oy = t - 165;  ox = 55; }
        int y0 = oy * 4 - 2, x0 = ox * 4 - 2;
        int ky0 = y0 < 0 ? -y0 : 0;
        int ky1 = (224 - y0) < 7 ? (224 - y0) : 7;
        int kx0 = x0 < 0 ? -x0 : 0;
        int kx1 = (224 - x0) < 7 ? (224 - x0) : 7;
        float acc = bv;
        for (int ci = 0; ci < 3; ci++) {
            const float* xp = xb + ci * 224 * 224;
            const float* wp = wsh + ci * 49;
            for (int ky = ky0; ky < ky1; ky++) {
                const float* row = xp + (y0 + ky) * 224 + x0;
                for (int kx = kx0; kx < kx1; kx++)
                    acc += row[kx] * wp[ky * 7 + kx];
            }
        }
        vals[oy * 56 + ox] = acc;
        s += (double)acc; s2 += (double)acc * (double)acc;
    }
    double ssum  = blockReduceSumD<16>(s, rbuf);
    double s2sum = blockReduceSumD<16>(s2, rbuf);
    double mean = ssum / 3136.0;
    double var  = s2sum / 3136.0 - mean * mean;         // biased (GN)
    double rstd = 1.0 / sqrt(var + EPSD);
    float sc = (float)((double)gw[c] * rstd);
    float sh = (float)((double)gb[c] - mean * (double)gw[c] * rstd);
    float* outp = out + ((size_t)b * 8 + c) * 3136;
    for (int idx = t; idx < 3136; idx += 1024) {
        float v = vals[idx] * sc + sh;
        outp[idx] = fmaxf(v, 0.f);
    }
}

// ---------------- stage B: conv1 (8->16, 5x5, s3, p1) + entropy-IN + ReLU ----------------
// One block per (b, c): 1024 blocks, 256 threads.
__global__ __launch_bounds__(256) void k_conv1_ent(const float* __restrict__ in,
                                                   const float* __restrict__ w,
                                                   const float* __restrict__ bias,
                                                   const float* __restrict__ nw,
                                                   const float* __restrict__ nb,
                                                   float* __restrict__ out) {
    __shared__ float vals[324];
    __shared__ float wsh[200];
    __shared__ float tab[26];
    __shared__ double rbuf[4];
    int b = blockIdx.x >> 4;
    int c = blockIdx.x & 15;
    int t = threadIdx.x;
    for (int i = t; i < 200; i += 256) wsh[i] = w[c * 200 + i];
    build_ent_tab(tab);
    __syncthreads();
    const float* xb = in + (size_t)b * 8 * 3136;
    float bv = bias[c];
    double s = 0.0, s2 = 0.0;
    // interior: oy,ox in [1,17] (289 px), guard-free
    for (int i = t; i < 289; i += 256) {
        int oy = 1 + i / 17, ox = 1 + i % 17;
        int y0 = oy * 3 - 1, x0 = ox * 3 - 1;
        float acc = bv;
        for (int ci = 0; ci < 8; ci++) {
            const float* xp = xb + ci * 3136 + y0 * 56 + x0;
            const float* wp = wsh + ci * 25;
#pragma unroll
            for (int ky = 0; ky < 5; ky++)
#pragma unroll
                for (int kx = 0; kx < 5; kx++)
                    acc += xp[ky * 56 + kx] * wp[ky * 5 + kx];
        }
        vals[oy * 18 + ox] = acc;
        s += (double)acc; s2 += (double)acc * (double)acc;
    }
    // boundary: row 0 (18) + col 0 rows 1..17 (17) = 35 px
    if (t < 35) {
        int oy = (t < 18) ? 0 : (t - 17);
        int ox = (t < 18) ? t : 0;
        int y0 = oy * 3 - 1, x0 = ox * 3 - 1;
        int ky0 = y0 < 0 ? 1 : 0;
        int kx0 = x0 < 0 ? 1 : 0;
        float acc = bv;
        for (int ci = 0; ci < 8; ci++) {
            const float* xp = xb + ci * 3136;
            const float* wp = wsh + ci * 25;
            for (int ky = ky0; ky < 5; ky++) {
                const float* row = xp + (y0 + ky) * 56 + x0;
                for (int kx = kx0; kx < 5; kx++)
                    acc += row[kx] * wp[ky * 5 + kx];
            }
        }
        vals[oy * 18 + ox] = acc;
        s += (double)acc; s2 += (double)acc * (double)acc;
    }
    __syncthreads();
    in_ent_epilogue(vals, rbuf, tab, s, s2, (double)nw[c], (double)nb[c],
                    out + ((size_t)b * 16 + c) * 324);
}

// ---------------- stage C: conv2 (16->32, 3x3, s1, p1) + entropy-IN + ReLU ----------------
// One block per (b, c): 2048 blocks, 256 threads. Input slab staged in LDS (f32, 20.7 KB).
__global__ __launch_bounds__(256) void k_conv2_ent(const float* __restrict__ in,
                                                   const float* __restrict__ w,
                                                   const float* __restrict__ bias,
                                                   const float* __restrict__ nw,
                                                   const float* __restrict__ nb,
                                                   float* __restrict__ out) {
    __shared__ float xin[5184];   // 16 * 324
    __shared__ float vals[324];
    __shared__ float wsh[144];
    __shared__ float tab[26];
    __shared__ double rbuf[4];
    int b = blockIdx.x >> 5;
    int c = blockIdx.x & 31;
    int t = threadIdx.x;
    const float* xb = in + (size_t)b * 5184;
    for (int i = t; i < 5184; i += 256) xin[i] = xb[i];
    for (int i = t; i < 144; i += 256) wsh[i] = w[c * 144 + i];
    build_ent_tab(tab);
    __syncthreads();
    float bv = bias[c];
    double s = 0.0, s2 = 0.0;
    // interior: oy,ox in [1,16] -> 256 px, exactly one per thread, guard-free
    {
        int oy = 1 + (t >> 4), ox = 1 + (t & 15);
        const float* base = xin + (oy - 1) * 18 + (ox - 1);
        float acc = bv;
        for (int ci = 0; ci < 16; ci++) {
            const float* xp = base + ci * 324;
            const float* wp = wsh + ci * 9;
#pragma unroll
            for (int ky = 0; ky < 3; ky++)
#pragma unroll
                for (int kx = 0; kx < 3; kx++)
                    acc += xp[ky * 18 + kx] * wp[ky * 3 + kx];
        }
        vals[oy * 18 + ox] = acc;
        s += (double)acc; s2 += (double)acc * (double)acc;
    }
    // boundary: rows 0,17 (36) + cols 0,17 rows 1..16 (32) = 68 px
    if (t < 68) {
        int oy, ox;
        if (t < 18)      { oy = 0;      ox = t; }
        else if (t < 36) { oy = 17;     ox = t - 18; }
        else if (t < 52) { oy = t - 35; ox = 0; }
        else             { oy = t - 51; ox = 17; }
        int y0 = oy - 1, x0 = ox - 1;
        int ky0 = y0 < 0 ? 1 : 0;
        int ky1 = (18 - y0) < 3 ? 2 : 3;
        int kx0 = x0 < 0 ? 1 : 0;
        int kx1 = (18 - x0) < 3 ? 2 : 3;
        float acc = bv;
        for (int ci = 0; ci < 16; ci++) {
            const float* xp = xin + ci * 324;
            const float* wp = wsh + ci * 9;
            for (int ky = ky0; ky < ky1; ky++) {
                const float* row = xp + (y0 + ky) * 18 + x0;
                for (int kx = kx0; kx < kx1; kx++)
                    acc += row[kx] * wp[ky * 3 + kx];
            }
        }
        vals[oy * 18 + ox] = acc;
        s += (double)acc; s2 += (double)acc * (double)acc;
    }
    __syncthreads();
    in_ent_epilogue(vals, rbuf, tab, s, s2, (double)nw[c], (double)nb[c],
                    out + ((size_t)b * 32 + c) * 324);
}

// ---------------- stage D1: BatchNorm1d batch stats folded to scale/shift ----------------
__global__ __launch_bounds__(256) void k_bnstats(const float* __restrict__ h2,
                                                 const float* __restrict__ g,
                                                 const float* __restrict__ bb,
                                                 float* __restrict__ scale,
                                                 float* __restrict__ shift) {
    int f = blockIdx.x * 256 + threadIdx.x;
    if (f >= 10368) return;
    double s = 0.0, s2 = 0.0;
    for (int b = 0; b < 64; b++) {
        double v = (double)h2[(size_t)b * 10368 + f];
        s += v; s2 += v * v;
    }
    double mean = s / 64.0;
    double var = s2 / 64.0 - mean * mean;   // biased (BN training)
    double rstd = 1.0 / sqrt(var + EPSD);
    double sc = (double)g[f] * rstd;
    scale[f] = (float)sc;
    shift[f] = (float)((double)bb[f] - mean * sc);
}

// ---------------- stage D2: fc1 with folded BN, + ReLU ----------------
// One block per (b, j): 2048 blocks.
__global__ __launch_bounds__(256) void k_fc1(const float* __restrict__ h2,
                                             const float* __restrict__ scale,
                                             const float* __restrict__ shift,
                                             const float* __restrict__ w1,
                                             const float* __restrict__ b1,
                                             float* __restrict__ fcout) {
    __shared__ double rbuf[4];
    int b = blockIdx.x >> 5;
    int j = blockIdx.x & 31;
    const float* hb = h2 + (size_t)b * 10368;
    const float* wj = w1 + (size_t)j * 10368;
    double acc = 0.0;
    for (int f = threadIdx.x; f < 10368; f += 256)
        acc += (double)((hb[f] * scale[f] + shift[f]) * wj[f]);
    acc = blockReduceSumD<4>(acc, rbuf);
    if (threadIdx.x == 0)
        fcout[b * 32 + j] = (float)fmax(acc + (double)b1[j], 0.0);
}

// ---------------- stage E: heads + softmax (f64 math, f32 out) ----------------
__global__ __launch_bounds__(64) void k_heads(const float* __restrict__ fc,
                                              const float* __restrict__ sw,
                                              const float* __restrict__ sb,
                                              const float* __restrict__ vw,
                                              const float* __restrict__ vb,
                                              float* __restrict__ out) {
    int b = threadIdx.x;
    double h[32];
#pragma unroll
    for (int i = 0; i < 32; i++) h[i] = (double)fc[b * 32 + i];
    double lg[5];
    double mx = -1e300;
#pragma unroll
    for (int k = 0; k < 5; k++) {
        double a = (double)sb[k];
#pragma unroll
        for (int i = 0; i < 32; i++) a += h[i] * (double)sw[k * 32 + i];
        lg[k] = a;
        mx = fmax(mx, a);
    }
    double se = 0.0;
#pragma unroll
    for (int k = 0; k < 5; k++) { lg[k] = exp(lg[k] - mx); se += lg[k]; }
#pragma unroll
    for (int k = 0; k < 5; k++) out[b * 5 + k] = (float)(lg[k] / se);
    double l0 = (double)vb[0], l1 = (double)vb[1];
#pragma unroll
    for (int i = 0; i < 32; i++) { l0 += h[i] * (double)vw[i]; l1 += h[i] * (double)vw[32 + i]; }
    double m = fmax(l0, l1);
    double e0 = exp(l0 - m), e1 = exp(l1 - m);
    double inv = 1.0 / (e0 + e1);
    out[320 + b * 2 + 0] = (float)(e0 * inv);
    out[320 + b * 2 + 1] = (float)(e1 * inv);
}

// ---------------- host launcher ----------------
extern "C" void kernel_launch(void* const* d_in, const int* in_sizes, int n_in,
                              void* d_out, int out_size, void* d_ws, size_t ws_size,
                              hipStream_t stream) {
    const float* x       = (const float*)d_in[0];
    const float* conv0_w = (const float*)d_in[1];
    const float* conv0_b = (const float*)d_in[2];
    const float* conv1_w = (const float*)d_in[3];
    const float* conv1_b = (const float*)d_in[4];
    const float* conv2_w = (const float*)d_in[5];
    const float* conv2_b = (const float*)d_in[6];
    const float* gn0_w   = (const float*)d_in[7];
    const float* gn0_b   = (const float*)d_in[8];
    const float* n1_w    = (const float*)d_in[9];
    const float* n1_b    = (const float*)d_in[10];
    const float* n2_w    = (const float*)d_in[11];
    const float* n2_b    = (const float*)d_in[12];
    const float* bn_g    = (const float*)d_in[13];
    const float* bn_b    = (const float*)d_in[14];
    const float* fc1_w   = (const float*)d_in[15];
    const float* fc1_b   = (const float*)d_in[16];
    const float* shape_w = (const float*)d_in[17];
    const float* shape_b = (const float*)d_in[18];
    const float* vern_w  = (const float*)d_in[19];
    const float* vern_b  = (const float*)d_in[20];
    float* out = (float*)d_out;

    float* ws = (float*)d_ws;
    float* h0    = ws;                    // 64*8*56*56   = 1605632
    float* h1    = h0 + 1605632;          // 64*16*18*18  = 331776
    float* h2    = h1 + 331776;           // 64*32*18*18  = 663552
    float* scale = h2 + 663552;           // 10368
    float* shift = scale + 10368;         // 10368
    float* fc    = shift + 10368;         // 64*32

    k_conv0_gn<<<dim3(512), dim3(1024), 0, stream>>>(x, conv0_w, conv0_b, gn0_w, gn0_b, h0);
    k_conv1_ent<<<dim3(1024), dim3(256), 0, stream>>>(h0, conv1_w, conv1_b, n1_w, n1_b, h1);
    k_conv2_ent<<<dim3(2048), dim3(256), 0, stream>>>(h1, conv2_w, conv2_b, n2_w, n2_b, h2);
    k_bnstats<<<dim3(41), dim3(256), 0, stream>>>(h2, bn_g, bn_b, scale, shift);
    k_fc1<<<dim3(2048), dim3(256), 0, stream>>>(h2, scale, shift, fc1_w, fc1_b, fc);
    k_heads<<<dim3(1), dim3(64), 0, stream>>>(fc, shape_w, shape_b, vern_w, vern_b, out);
}